// Round 5
// baseline (1158.172 us; speedup 1.0000x reference)
//
#include <hip/hip_runtime.h>
#include <math.h>

#define TT 36
#define NP 160
#define KDIM 641
#define PP 512
#define KPAD 704          // LDS/transposed-x row pad; pads stay zero
#define ZERO_SLOT 664     // guaranteed-zero LDS slot (never written)
#define DUMP_SLOT 672     // garbage sink for unit 0's phantom minus-row
#define NU 321            // pair-units: u=0 const col; 1..160 cos; 161..320 sin
#define BT 384            // 6 waves
#define LAM 0.1f
#define EPSW 0.01f
#define NITER 200
#define NPOW 160

// ---------------- dictionary ----------------
__global__ void k_build_dic(const float* __restrict__ rr, const float* __restrict__ th,
                            float* __restrict__ D, float* __restrict__ outD) {
  int idx = blockIdx.x * blockDim.x + threadIdx.x;
  if (idx >= TT * KDIM) return;
  int t = idx / KDIM, k = idx % KDIM;
  float v;
  if (k == 0) {
    v = 1.0f;
  } else {
    int g = (k - 1) / NP;     // 0:p*cos 1:m*cos 2:p*sin 3:m*sin
    int p = (k - 1) % NP;
    float ft = (float)t;
    float pw = powf(rr[p], ft);
    if ((g == 1 || g == 3) && (t & 1)) pw = -pw;
    float ang = ft * th[p];
    v = pw * ((g < 2) ? cosf(ang) : sinf(ang));
  }
  D[idx] = v;
  outD[idx] = v;
}

// ---------------- G = D D^T (36x36) ----------------
__global__ void k_G(const float* __restrict__ D, float* __restrict__ G) {
  int idx = blockIdx.x * blockDim.x + threadIdx.x;
  if (idx >= TT * TT) return;
  int i = idx / TT, j = idx % TT;
  float s = 0.0f;
  for (int k = 0; k < KDIM; ++k) s = fmaf(D[i * KDIM + k], D[j * KDIM + k], s);
  G[idx] = s;
}

// ---------------- power iteration on 36x36 (one wave): L = ||DtD||_2 ----------------
__global__ void k_power(const float* __restrict__ G, float* __restrict__ Lb) {
  int lane = threadIdx.x;   // blockDim = 64
  float g[TT];
#pragma unroll
  for (int j = 0; j < TT; ++j) g[j] = (lane < TT) ? G[lane * TT + j] : 0.0f;
  float v = (lane < TT) ? 1.0f : 0.0f;
  for (int it = 0; it < NPOW; ++it) {
    float u = 0.0f;
#pragma unroll
    for (int j = 0; j < TT; ++j) u = fmaf(g[j], __shfl(v, j, 64), u);
    float s = u * u;
#pragma unroll
    for (int o = 32; o >= 1; o >>= 1) s += __shfl_xor(s, o, 64);
    v = u * rsqrtf(s);
  }
  float u = 0.0f;
#pragma unroll
  for (int j = 0; j < TT; ++j) u = fmaf(g[j], __shfl(v, j, 64), u);
  float num = v * u, den = v * v;
#pragma unroll
  for (int o = 32; o >= 1; o >>= 1) {
    num += __shfl_xor(num, o, 64);
    den += __shfl_xor(den, o, 64);
  }
  if (lane == 0) {
    float L = num / den;   // Rayleigh quotient = lambda_max
    Lb[0] = L;
    Lb[1] = 1.0f / L;
    Lb[3] = 0.0f;          // reset norm accumulator (graph-replay safe)
  }
}

// ---- DPP wave-64 sum; total valid in lane 63 ----
template <int C>
__device__ __forceinline__ float dppadd(float v) {
  int t = __builtin_amdgcn_update_dpp(0, __float_as_int(v), C, 0xf, 0xf, true);
  return v + __int_as_float(t);
}
__device__ __forceinline__ float wave_sum63(float v) {
  v = dppadd<0xB1>(v);    // quad_perm [1,0,3,2]
  v = dppadd<0x4E>(v);    // quad_perm [2,3,0,1]
  v = dppadd<0x141>(v);   // row_half_mirror
  v = dppadd<0x140>(v);   // row_mirror
  v = dppadd<0x142>(v);   // row_bcast15
  v = dppadd<0x143>(v);   // row_bcast31
  return v;
}

// ---------------- persistent per-round FISTA: one column per block, 6 waves ----------------
__global__ __attribute__((amdgpu_flat_work_group_size(BT, BT), amdgpu_waves_per_eu(3, 3)))
void k_round(
    const float* __restrict__ Dg, const float* __restrict__ X,
    float* __restrict__ Lb, const float* __restrict__ xprev,
    float* __restrict__ xout, int first, int last) {
  __shared__ __align__(16) float ylds[KPAD];
  __shared__ __align__(16) float zlds[TT];

  const int tid  = threadIdx.x;
  const int lane = tid & 63;
  const int g    = tid >> 6;          // wave 0..5
  const int t0   = g * 6;             // this wave's z-rows: t0..t0+5 (t0 even)
  const int p    = blockIdx.x;        // column

  const float Linv = Lb[1];
  const float lamL = LAM * Linv;

  // ---- phase-2 pair-unit: rows kP (plus-group) and kM = (-1)^t * same column
  const int u = tid;
  const bool act = (u < NU);
  int kP, kM;
  if (u == 0)        { kP = 0;        kM = DUMP_SLOT; }
  else if (u < 161)  { kP = u;        kM = u + 160; }
  else if (u < NU)   { kP = u + 160;  kM = u + 320; }
  else               { kP = 0;        kM = DUMP_SLOT; }

  // ---- phase-1 unit mapping: unit u1 = lane + 64j, j<6 (u1<321 active)
  int kA[6], kB[6];
#pragma unroll
  for (int j = 0; j < 6; ++j) {
    const int u1 = lane + 64 * j;
    int ka, kb;
    if (u1 == 0)        { ka = 0;        kb = ZERO_SLOT; }
    else if (u1 < 161)  { ka = u1;       kb = u1 + 160; }
    else if (u1 < NU)   { ka = u1 + 160; kb = u1 + 320; }
    else                { ka = ZERO_SLOT; kb = ZERO_SLOT; }
    kA[j] = ka; kB[j] = kb;
  }

  // Dq[ii][j] = D[t0+ii][kA[j]] (plus-group value); 0 if inactive
  float Dq[6][6];
#pragma unroll
  for (int ii = 0; ii < 6; ++ii)
#pragma unroll
    for (int j = 0; j < 6; ++j) {
      const int u1 = lane + 64 * j;
      Dq[ii][j] = (u1 < NU) ? Dg[(t0 + ii) * KDIM + kA[j]] : 0.0f;
    }

  // ---- phase-2 D column (plus member) in registers — coalesced across lanes
  float Dcp[TT];
#pragma unroll
  for (int t = 0; t < TT; ++t) Dcp[t] = Dg[t * KDIM + kP];

  // ---- c0 = Linv * (D^T x_col) for both rows via even/odd split; cm/cp thresholds
  float cmP, cpP, cmM, cpM;
  {
    float sE = 0.f, sO = 0.f;
#pragma unroll
    for (int t = 0; t < TT; ++t) {
      const float xv = X[t * PP + p];       // same addr block-wide: broadcast
      if (t & 1) sO = fmaf(Dcp[t], xv, sO);
      else       sE = fmaf(Dcp[t], xv, sE);
    }
    const float c0P = (sE + sO) * Linv;
    const float c0M = (sE - sO) * Linv;
    float wlP = lamL, wlM = lamL;
    if (!first) {
      const float nl = lamL * Lb[2];        // lam*Linv/||wr||
      const float apP = fabsf(xprev[p * KPAD + kP]);
      const float apM = fabsf(xprev[p * KPAD + ((u > 0 && act) ? kM : kP)]);
      wlP = nl / (apP + EPSW);
      wlM = nl / (apM + EPSW);
    }
    cmP = c0P - wlP; cpP = c0P + wlP;
    cmM = c0M - wlM; cpM = c0M + wlM;
  }

  // ---- zero y in LDS (incl. pads: ZERO_SLOT must stay 0 forever)
  for (int i = tid; i < KPAD; i += BT) ylds[i] = 0.0f;

  float xP = 0.f, xM = 0.f, yP = 0.f, yM = 0.f;
  float tmom = 1.0f;

  __syncthreads();

  for (int it = 0; it < NITER; ++it) {
    // ===== phase 1: z = Linv * (D @ y), pole-paired; rows t0..t0+5 =====
    float acc[6];
#pragma unroll
    for (int ii = 0; ii < 6; ++ii) acc[ii] = 0.f;
#pragma unroll
    for (int j = 0; j < 6; ++j) {
      const float yA = ylds[kA[j]];
      const float yB = ylds[kB[j]];
      const float a = yA + yB;              // even-t operand (t0 even => ii parity = t parity)
      const float b = yA - yB;              // odd-t operand
#pragma unroll
      for (int ii = 0; ii < 6; ++ii)
        acc[ii] = fmaf(Dq[ii][j], (ii & 1) ? b : a, acc[ii]);
    }
#pragma unroll
    for (int ii = 0; ii < 6; ++ii) acc[ii] = wave_sum63(acc[ii]);
    if (lane == 63) {
#pragma unroll
      for (int ii = 0; ii < 6; ++ii) zlds[t0 + ii] = acc[ii] * Linv;
    }
    __syncthreads();

    // ===== phase 2: both rows of the pair via even/odd sums =====
    const float tn = 0.5f * (1.0f + sqrtf(1.0f + 4.0f * tmom * tmom));
    const float mu = (tmom - 1.0f) / tn;
    tmom = tn;

    float sE = 0.f, sO = 0.f;
#pragma unroll
    for (int q = 0; q < 9; ++q) {
      const float4 z4 = *reinterpret_cast<const float4*>(&zlds[4 * q]);  // broadcast
      sE = fmaf(Dcp[4*q+0], z4.x, sE);
      sO = fmaf(Dcp[4*q+1], z4.y, sO);
      sE = fmaf(Dcp[4*q+2], z4.z, sE);
      sO = fmaf(Dcp[4*q+3], z4.w, sO);
    }
    const float sP = sE + sO;
    const float sM = sE - sO;
    {
      float uu, xn;
      uu = yP - sP; xn = fmaxf(0.f, uu + cmP) + fminf(0.f, uu + cpP);
      yP = fmaf(mu, xn - xP, xn); xP = xn;
      uu = yM - sM; xn = fmaxf(0.f, uu + cmM) + fminf(0.f, uu + cpM);
      yM = fmaf(mu, xn - xM, xn); xM = xn;
    }
    if (act) {
      ylds[kP] = yP;
      ylds[kM] = yM;      // u=0 dumps into DUMP_SLOT (never read)
    }
    __syncthreads();
  }

  // ---- emit x
  if (act) {
    if (last) {
      xout[kP * PP + p] = xP;
      if (u > 0) xout[kM * PP + p] = xM;
    } else {
      xout[p * KPAD + kP] = xP;             // transposed: coalesced
      if (u > 0) xout[p * KPAD + kM] = xM;
    }
  }

  // ---- fused reweight-norm accumulation: sum of wr^2 over this column
  if (!last) {
    float rP = act ? 1.0f / (fabsf(xP) + EPSW) : 0.0f;
    float rM = (act && u > 0) ? 1.0f / (fabsf(xM) + EPSW) : 0.0f;
    float s = rP * rP + rM * rM;
    s = wave_sum63(s);
    if (lane == 63) zlds[g] = s;
    __syncthreads();
    if (tid == 0) {
      float tot = 0.f;
#pragma unroll
      for (int i = 0; i < 6; ++i) tot += zlds[i];
      atomicAdd(&Lb[3], tot);
    }
  }
}

// ---------------- finalize norm: Lb[2] = 1/||wr||, reset accumulator ----------------
__global__ void k_norm(float* __restrict__ Lb) {
  if (threadIdx.x == 0) {
    Lb[2] = 1.0f / sqrtf(Lb[3]);
    Lb[3] = 0.0f;
  }
}

// ---------------- host ----------------
extern "C" void kernel_launch(void* const* d_in, const int* in_sizes, int n_in,
                              void* d_out, int out_size, void* d_ws, size_t ws_size,
                              hipStream_t stream) {
  const float* x  = (const float*)d_in[0];
  const float* rr = (const float*)d_in[1];
  const float* th = (const float*)d_in[2];
  float* out = (float*)d_out;
  float* ws  = (float*)d_ws;

  size_t off = 0;
  auto alloc = [&](size_t n) {
    float* p = ws + off;
    off += (n + 63) & ~(size_t)63;
    return p;
  };
  float* D    = alloc((size_t)TT * KDIM);
  float* G    = alloc(TT * TT);
  float* Lb   = alloc(16);
  float* xa   = alloc((size_t)PP * KPAD);   // transposed intermediate x
  if (off * sizeof(float) > ws_size) return;

  k_build_dic<<<(TT * KDIM + 255) / 256, 256, 0, stream>>>(rr, th, D, out + (size_t)KDIM * PP);
  k_G<<<(TT * TT + 255) / 256, 256, 0, stream>>>(D, G);
  k_power<<<1, 64, 0, stream>>>(G, Lb);

  for (int r = 0; r < 3; ++r) {
    const int first = (r == 0), last = (r == 2);
    float* xo = last ? out : xa;
    k_round<<<PP, BT, 0, stream>>>(D, x, Lb, xa, xo, first, last);
    if (!last) k_norm<<<1, 64, 0, stream>>>(Lb);
  }
}

// Round 6
// 879.311 us; speedup vs baseline: 1.3171x; 1.3171x over previous
//
#include <hip/hip_runtime.h>
#include <math.h>

#define TT 36
#define NP 160
#define KDIM 641
#define PP 512
#define KPAD 704          // LDS y pad / transposed-x row stride; pads stay zero
#define ZERO_SLOT 664     // guaranteed-zero LDS slot (never written)
#define DUMP_SLOT 672     // garbage sink for unit 0's phantom minus-row
#define NU 321            // pair-units: u=0 const col; 1..160 cos; 161..320 sin
#define BT 256            // 4 waves
#define LAM 0.1f
#define EPSW 0.01f
#define NITER 200
#define NPOW 160

// ---------------- dictionary ----------------
__global__ void k_build_dic(const float* __restrict__ rr, const float* __restrict__ th,
                            float* __restrict__ D, float* __restrict__ outD) {
  int idx = blockIdx.x * blockDim.x + threadIdx.x;
  if (idx >= TT * KDIM) return;
  int t = idx / KDIM, k = idx % KDIM;
  float v;
  if (k == 0) {
    v = 1.0f;
  } else {
    int g = (k - 1) / NP;     // 0:p*cos 1:m*cos 2:p*sin 3:m*sin
    int p = (k - 1) % NP;
    float ft = (float)t;
    float pw = powf(rr[p], ft);
    if ((g == 1 || g == 3) && (t & 1)) pw = -pw;
    float ang = ft * th[p];
    v = pw * ((g < 2) ? cosf(ang) : sinf(ang));
  }
  D[idx] = v;
  outD[idx] = v;
}

// ---------------- G = D D^T (36x36) ----------------
__global__ void k_G(const float* __restrict__ D, float* __restrict__ G) {
  int idx = blockIdx.x * blockDim.x + threadIdx.x;
  if (idx >= TT * TT) return;
  int i = idx / TT, j = idx % TT;
  float s = 0.0f;
  for (int k = 0; k < KDIM; ++k) s = fmaf(D[i * KDIM + k], D[j * KDIM + k], s);
  G[idx] = s;
}

// ---------------- power iteration on 36x36 (one wave): L = ||DtD||_2 ----------------
__global__ void k_power(const float* __restrict__ G, float* __restrict__ Lb) {
  int lane = threadIdx.x;   // blockDim = 64
  float g[TT];
#pragma unroll
  for (int j = 0; j < TT; ++j) g[j] = (lane < TT) ? G[lane * TT + j] : 0.0f;
  float v = (lane < TT) ? 1.0f : 0.0f;
  for (int it = 0; it < NPOW; ++it) {
    float u = 0.0f;
#pragma unroll
    for (int j = 0; j < TT; ++j) u = fmaf(g[j], __shfl(v, j, 64), u);
    float s = u * u;
#pragma unroll
    for (int o = 32; o >= 1; o >>= 1) s += __shfl_xor(s, o, 64);
    v = u * rsqrtf(s);
  }
  float u = 0.0f;
#pragma unroll
  for (int j = 0; j < TT; ++j) u = fmaf(g[j], __shfl(v, j, 64), u);
  float num = v * u, den = v * v;
#pragma unroll
  for (int o = 32; o >= 1; o >>= 1) {
    num += __shfl_xor(num, o, 64);
    den += __shfl_xor(den, o, 64);
  }
  if (lane == 0) {
    float L = num / den;   // Rayleigh quotient = lambda_max
    Lb[0] = L;
    Lb[1] = 1.0f / L;
    Lb[3] = 0.0f;          // reset norm accumulator (graph-replay safe)
  }
}

// ---- DPP wave-64 sum; total valid in lane 63 ----
template <int C>
__device__ __forceinline__ float dppadd(float v) {
  int t = __builtin_amdgcn_update_dpp(0, __float_as_int(v), C, 0xf, 0xf, true);
  return v + __int_as_float(t);
}
__device__ __forceinline__ float wave_sum63(float v) {
  v = dppadd<0xB1>(v);    // quad_perm [1,0,3,2]
  v = dppadd<0x4E>(v);    // quad_perm [2,3,0,1]
  v = dppadd<0x141>(v);   // row_half_mirror
  v = dppadd<0x140>(v);   // row_mirror
  v = dppadd<0x142>(v);   // row_bcast15
  v = dppadd<0x143>(v);   // row_bcast31
  return v;
}

// map pair-unit u -> (kP, kM)
__device__ __forceinline__ void unit_map(int u, int& kP, int& kM) {
  if (u == 0)       { kP = 0;        kM = DUMP_SLOT; }
  else if (u < 161) { kP = u;        kM = u + 160; }
  else              { kP = u + 160;  kM = u + 320; }
}

// ---------------- persistent per-round FISTA: one column per block, 4 waves ----------------
__global__ __launch_bounds__(BT, 1) void k_round(
    const float* __restrict__ Dg, const float* __restrict__ X,
    float* __restrict__ Lb, const float* __restrict__ xprev,
    float* __restrict__ xout, int first, int last) {
  __shared__ __align__(16) float ylds[KPAD];
  __shared__ __align__(16) float zlds[TT];

  const int tid  = threadIdx.x;
  const int lane = tid & 63;
  const int g    = tid >> 6;          // wave 0..3
  const int t0   = g * 9;             // this wave's z-rows: t0..t0+8
  const bool gOdd = (g & 1);          // t0 parity (9 odd)
  const int p    = blockIdx.x;        // column

  const float Linv = Lb[1];
  const float lamL = LAM * Linv;

  // ---- phase-2 pair-units: u1 = tid (always active), u2 = tid+256 (tid<65)
  const int u1 = tid;
  const int u2 = tid + 256;
  const bool act2 = (u2 < NU);
  int kP1, kM1, kP2, kM2;
  unit_map(u1, kP1, kM1);
  unit_map(act2 ? u2 : 0, kP2, kM2);

  // ---- phase-1 unit mapping: unit ua = lane + 64j, j<6 (ua<321 active)
  int kA[6], kB[6];
#pragma unroll
  for (int j = 0; j < 6; ++j) {
    const int ua = lane + 64 * j;
    int ka, kb;
    if (ua == 0)       { ka = 0;        kb = ZERO_SLOT; }
    else if (ua < 161) { ka = ua;       kb = ua + 160; }
    else if (ua < NU)  { ka = ua + 160; kb = ua + 320; }
    else               { ka = ZERO_SLOT; kb = ZERO_SLOT; }
    kA[j] = ka; kB[j] = kb;
  }

  // Dq[ii][j] = D[t0+ii][kA[j]] (plus-group value); 0 if inactive
  float Dq[9][6];
#pragma unroll
  for (int ii = 0; ii < 9; ++ii)
#pragma unroll
    for (int j = 0; j < 6; ++j) {
      const int ua = lane + 64 * j;
      Dq[ii][j] = (ua < NU) ? Dg[(t0 + ii) * KDIM + kA[j]] : 0.0f;
    }

  // ---- phase-2 D columns (plus member of each pair) in registers
  float Dca[TT], Dcb[TT];
#pragma unroll
  for (int t = 0; t < TT; ++t) {
    Dca[t] = Dg[t * KDIM + kP1];
    Dcb[t] = act2 ? Dg[t * KDIM + kP2] : 0.0f;
  }

  // ---- c0 = Linv * (D^T x_col) via even/odd split; cm/cp thresholds (both units)
  float cmP1, cpP1, cmM1, cpM1, cmP2, cpP2, cmM2, cpM2;
  {
    float sE1 = 0.f, sO1 = 0.f, sE2 = 0.f, sO2 = 0.f;
#pragma unroll
    for (int t = 0; t < TT; ++t) {
      const float xv = X[t * PP + p];       // block-uniform: broadcast
      if (t & 1) { sO1 = fmaf(Dca[t], xv, sO1); sO2 = fmaf(Dcb[t], xv, sO2); }
      else       { sE1 = fmaf(Dca[t], xv, sE1); sE2 = fmaf(Dcb[t], xv, sE2); }
    }
    const float c0P1 = (sE1 + sO1) * Linv, c0M1 = (sE1 - sO1) * Linv;
    const float c0P2 = (sE2 + sO2) * Linv, c0M2 = (sE2 - sO2) * Linv;
    float wlP1 = lamL, wlM1 = lamL, wlP2 = lamL, wlM2 = lamL;
    if (!first) {
      const float nl = lamL * Lb[2];        // lam*Linv/||wr||
      wlP1 = nl / (fabsf(xprev[p * KPAD + kP1]) + EPSW);
      wlM1 = nl / (fabsf(xprev[p * KPAD + ((u1 > 0) ? kM1 : kP1)]) + EPSW);
      if (act2) {
        wlP2 = nl / (fabsf(xprev[p * KPAD + kP2]) + EPSW);
        wlM2 = nl / (fabsf(xprev[p * KPAD + kM2]) + EPSW);
      }
    }
    cmP1 = c0P1 - wlP1; cpP1 = c0P1 + wlP1;
    cmM1 = c0M1 - wlM1; cpM1 = c0M1 + wlM1;
    cmP2 = c0P2 - wlP2; cpP2 = c0P2 + wlP2;
    cmM2 = c0M2 - wlM2; cpM2 = c0M2 + wlM2;
  }

  // ---- zero y in LDS (incl. pads: ZERO_SLOT must stay 0 forever)
  for (int i = tid; i < KPAD; i += BT) ylds[i] = 0.0f;

  float xP1 = 0.f, xM1 = 0.f, yP1 = 0.f, yM1 = 0.f;
  float xP2 = 0.f, xM2 = 0.f, yP2 = 0.f, yM2 = 0.f;
  float tmom = 1.0f;

  __syncthreads();

  for (int it = 0; it < NITER; ++it) {
    // ===== phase 1: z = Linv * (D @ y), pole-paired; rows t0..t0+8 =====
    float acc[9];
#pragma unroll
    for (int ii = 0; ii < 9; ++ii) acc[ii] = 0.f;
#pragma unroll
    for (int j = 0; j < 6; ++j) {
      const float yA = ylds[kA[j]];
      const float yB = ylds[kB[j]];
      const float a = yA + yB;              // even-t operand
      const float b = yA - yB;              // odd-t operand
      const float e0 = gOdd ? b : a;        // operand for even ii
      const float e1 = gOdd ? a : b;        // operand for odd ii
#pragma unroll
      for (int ii = 0; ii < 9; ++ii)
        acc[ii] = fmaf(Dq[ii][j], (ii & 1) ? e1 : e0, acc[ii]);
    }
#pragma unroll
    for (int ii = 0; ii < 9; ++ii) acc[ii] = wave_sum63(acc[ii]);
    if (lane == 63) {
#pragma unroll
      for (int ii = 0; ii < 9; ++ii) zlds[t0 + ii] = acc[ii] * Linv;
    }
    __syncthreads();

    // ===== phase 2: both rows of each pair via even/odd sums =====
    const float tn = 0.5f * (1.0f + sqrtf(1.0f + 4.0f * tmom * tmom));
    const float mu = (tmom - 1.0f) / tn;
    tmom = tn;

    float sE1 = 0.f, sO1 = 0.f;
#pragma unroll
    for (int q = 0; q < 9; ++q) {
      const float4 z4 = *reinterpret_cast<const float4*>(&zlds[4 * q]);  // broadcast
      sE1 = fmaf(Dca[4*q+0], z4.x, sE1);
      sO1 = fmaf(Dca[4*q+1], z4.y, sO1);
      sE1 = fmaf(Dca[4*q+2], z4.z, sE1);
      sO1 = fmaf(Dca[4*q+3], z4.w, sO1);
    }
    {
      const float sP = sE1 + sO1, sM = sE1 - sO1;
      float uu, xn;
      uu = yP1 - sP; xn = fmaxf(0.f, uu + cmP1) + fminf(0.f, uu + cpP1);
      yP1 = fmaf(mu, xn - xP1, xn); xP1 = xn;
      uu = yM1 - sM; xn = fmaxf(0.f, uu + cmM1) + fminf(0.f, uu + cpM1);
      yM1 = fmaf(mu, xn - xM1, xn); xM1 = xn;
      ylds[kP1] = yP1;
      ylds[kM1] = yM1;            // u1=0 dumps into DUMP_SLOT (never read)
    }
    if (act2) {
      float sE2 = 0.f, sO2 = 0.f;
#pragma unroll
      for (int q = 0; q < 9; ++q) {
        const float4 z4 = *reinterpret_cast<const float4*>(&zlds[4 * q]);
        sE2 = fmaf(Dcb[4*q+0], z4.x, sE2);
        sO2 = fmaf(Dcb[4*q+1], z4.y, sO2);
        sE2 = fmaf(Dcb[4*q+2], z4.z, sE2);
        sO2 = fmaf(Dcb[4*q+3], z4.w, sO2);
      }
      const float sP = sE2 + sO2, sM = sE2 - sO2;
      float uu, xn;
      uu = yP2 - sP; xn = fmaxf(0.f, uu + cmP2) + fminf(0.f, uu + cpP2);
      yP2 = fmaf(mu, xn - xP2, xn); xP2 = xn;
      uu = yM2 - sM; xn = fmaxf(0.f, uu + cmM2) + fminf(0.f, uu + cpM2);
      yM2 = fmaf(mu, xn - xM2, xn); xM2 = xn;
      ylds[kP2] = yP2;
      ylds[kM2] = yM2;
    }
    __syncthreads();
  }

  // ---- emit x
  if (last) {
    xout[kP1 * PP + p] = xP1;
    if (u1 > 0) xout[kM1 * PP + p] = xM1;
    if (act2) { xout[kP2 * PP + p] = xP2; xout[kM2 * PP + p] = xM2; }
  } else {
    xout[p * KPAD + kP1] = xP1;           // transposed: coalesced-ish
    if (u1 > 0) xout[p * KPAD + kM1] = xM1;
    if (act2) { xout[p * KPAD + kP2] = xP2; xout[p * KPAD + kM2] = xM2; }
  }

  // ---- fused reweight-norm accumulation: sum of wr^2 over this column
  if (!last) {
    float r0 = 1.0f / (fabsf(xP1) + EPSW);
    float s = r0 * r0;
    if (u1 > 0) { float r = 1.0f / (fabsf(xM1) + EPSW); s += r * r; }
    if (act2) {
      float ra = 1.0f / (fabsf(xP2) + EPSW);
      float rb = 1.0f / (fabsf(xM2) + EPSW);
      s += ra * ra + rb * rb;
    }
    s = wave_sum63(s);
    __syncthreads();                      // zlds free after loop
    if (lane == 63) zlds[g] = s;
    __syncthreads();
    if (tid == 0) {
      float tot = zlds[0] + zlds[1] + zlds[2] + zlds[3];
      atomicAdd(&Lb[3], tot);
    }
  }
}

// ---------------- finalize norm: Lb[2] = 1/||wr||, reset accumulator ----------------
__global__ void k_norm(float* __restrict__ Lb) {
  if (threadIdx.x == 0) {
    Lb[2] = 1.0f / sqrtf(Lb[3]);
    Lb[3] = 0.0f;
  }
}

// ---------------- host ----------------
extern "C" void kernel_launch(void* const* d_in, const int* in_sizes, int n_in,
                              void* d_out, int out_size, void* d_ws, size_t ws_size,
                              hipStream_t stream) {
  const float* x  = (const float*)d_in[0];
  const float* rr = (const float*)d_in[1];
  const float* th = (const float*)d_in[2];
  float* out = (float*)d_out;
  float* ws  = (float*)d_ws;

  size_t off = 0;
  auto alloc = [&](size_t n) {
    float* p = ws + off;
    off += (n + 63) & ~(size_t)63;
    return p;
  };
  float* D    = alloc((size_t)TT * KDIM);
  float* G    = alloc(TT * TT);
  float* Lb   = alloc(16);
  float* xa   = alloc((size_t)PP * KPAD);   // transposed intermediate x
  if (off * sizeof(float) > ws_size) return;

  k_build_dic<<<(TT * KDIM + 255) / 256, 256, 0, stream>>>(rr, th, D, out + (size_t)KDIM * PP);
  k_G<<<(TT * TT + 255) / 256, 256, 0, stream>>>(D, G);
  k_power<<<1, 64, 0, stream>>>(G, Lb);

  for (int r = 0; r < 3; ++r) {
    const int first = (r == 0), last = (r == 2);
    float* xo = last ? out : xa;
    k_round<<<PP, BT, 0, stream>>>(D, x, Lb, xa, xo, first, last);
    if (!last) k_norm<<<1, 64, 0, stream>>>(Lb);
  }
}

// Round 7
// 821.254 us; speedup vs baseline: 1.4102x; 1.0707x over previous
//
#include <hip/hip_runtime.h>
#include <math.h>

#define TT 36
#define NP 160
#define KDIM 641
#define PP 512
#define KPAD 704          // LDS y pad / transposed-x row stride; pads stay zero
#define ZERO_SLOT 664     // guaranteed-zero LDS slot (never written)
#define DUMP_SLOT 672     // garbage sink for unit 0's phantom minus-row
#define NU 321            // pair-units: u=0 const col; 1..160 cos; 161..320 sin
#define BT 512            // 8 waves
#define LAM 0.1f
#define EPSW 0.01f
#define NITER 200
#define NPOW 160

// ---------------- dictionary ----------------
__global__ void k_build_dic(const float* __restrict__ rr, const float* __restrict__ th,
                            float* __restrict__ D, float* __restrict__ outD) {
  int idx = blockIdx.x * blockDim.x + threadIdx.x;
  if (idx >= TT * KDIM) return;
  int t = idx / KDIM, k = idx % KDIM;
  float v;
  if (k == 0) {
    v = 1.0f;
  } else {
    int g = (k - 1) / NP;     // 0:p*cos 1:m*cos 2:p*sin 3:m*sin
    int p = (k - 1) % NP;
    float ft = (float)t;
    float pw = powf(rr[p], ft);
    if ((g == 1 || g == 3) && (t & 1)) pw = -pw;
    float ang = ft * th[p];
    v = pw * ((g < 2) ? cosf(ang) : sinf(ang));
  }
  D[idx] = v;
  outD[idx] = v;
}

// ---------------- G = D D^T (36x36) ----------------
__global__ void k_G(const float* __restrict__ D, float* __restrict__ G) {
  int idx = blockIdx.x * blockDim.x + threadIdx.x;
  if (idx >= TT * TT) return;
  int i = idx / TT, j = idx % TT;
  float s = 0.0f;
  for (int k = 0; k < KDIM; ++k) s = fmaf(D[i * KDIM + k], D[j * KDIM + k], s);
  G[idx] = s;
}

// ---------------- power iteration on 36x36 (one wave): L = ||DtD||_2 ----------------
__global__ void k_power(const float* __restrict__ G, float* __restrict__ Lb) {
  int lane = threadIdx.x;   // blockDim = 64
  float g[TT];
#pragma unroll
  for (int j = 0; j < TT; ++j) g[j] = (lane < TT) ? G[lane * TT + j] : 0.0f;
  float v = (lane < TT) ? 1.0f : 0.0f;
  for (int it = 0; it < NPOW; ++it) {
    float u = 0.0f;
#pragma unroll
    for (int j = 0; j < TT; ++j) u = fmaf(g[j], __shfl(v, j, 64), u);
    float s = u * u;
#pragma unroll
    for (int o = 32; o >= 1; o >>= 1) s += __shfl_xor(s, o, 64);
    v = u * rsqrtf(s);
  }
  float u = 0.0f;
#pragma unroll
  for (int j = 0; j < TT; ++j) u = fmaf(g[j], __shfl(v, j, 64), u);
  float num = v * u, den = v * v;
#pragma unroll
  for (int o = 32; o >= 1; o >>= 1) {
    num += __shfl_xor(num, o, 64);
    den += __shfl_xor(den, o, 64);
  }
  if (lane == 0) {
    float L = num / den;   // Rayleigh quotient = lambda_max
    Lb[0] = L;
    Lb[1] = 1.0f / L;
    Lb[3] = 0.0f;          // reset norm accumulator (graph-replay safe)
  }
}

// ---- DPP wave-64 sum; total valid in lane 63 ----
template <int C>
__device__ __forceinline__ float dppadd(float v) {
  int t = __builtin_amdgcn_update_dpp(0, __float_as_int(v), C, 0xf, 0xf, true);
  return v + __int_as_float(t);
}
__device__ __forceinline__ float wave_sum63(float v) {
  v = dppadd<0xB1>(v);    // quad_perm [1,0,3,2]
  v = dppadd<0x4E>(v);    // quad_perm [2,3,0,1]
  v = dppadd<0x141>(v);   // row_half_mirror
  v = dppadd<0x140>(v);   // row_mirror
  v = dppadd<0x142>(v);   // row_bcast15
  v = dppadd<0x143>(v);   // row_bcast31
  return v;
}

// map pair-unit u -> (kP, kM)
__device__ __forceinline__ void unit_map(int u, int& kP, int& kM) {
  if (u == 0)       { kP = 0;        kM = DUMP_SLOT; }
  else if (u < 161) { kP = u;        kM = u + 160; }
  else              { kP = u + 160;  kM = u + 320; }
}

// ---------------- persistent per-round FISTA: one column per block, 8 waves ----------------
__global__ __launch_bounds__(BT, 4) void k_round(
    const float* __restrict__ Dg, const float* __restrict__ X,
    float* __restrict__ Lb, const float* __restrict__ xprev,
    float* __restrict__ xout, int first, int last) {
  __shared__ __align__(16) float ylds[KPAD];
  __shared__ __align__(16) float zlds[40];

  const int tid  = threadIdx.x;
  const int lane = tid & 63;
  const int w    = tid >> 6;          // wave 0..7
  const int nr   = (w < 4) ? 5 : 4;   // rows owned: t = w + 8i, i < nr
  const float sgn = (w & 1) ? -1.0f : 1.0f;   // row parity uniform per wave
  const int p    = blockIdx.x;        // column

  const float Linv = Lb[1];
  const float lamL = LAM * Linv;

  // ---- phase-2 pair-unit: one per thread (tid < NU)
  const int u = tid;
  const bool act = (u < NU);
  int kP, kM;
  unit_map(act ? u : 0, kP, kM);

  // ---- phase-1 unit mapping: unit ua = lane + 64j, j<6 (ua<321 active)
  int kA[6], kB[6];
#pragma unroll
  for (int j = 0; j < 6; ++j) {
    const int ua = lane + 64 * j;
    int ka, kb;
    if (ua == 0)       { ka = 0;        kb = ZERO_SLOT; }
    else if (ua < 161) { ka = ua;       kb = ua + 160; }
    else if (ua < NU)  { ka = ua + 160; kb = ua + 320; }
    else               { ka = ZERO_SLOT; kb = ZERO_SLOT; }
    kA[j] = ka; kB[j] = kb;
  }

  // Dq[i][j] = D[w+8i][kA[j]] (plus-group value); 0 if inactive
  float Dq[5][6];
#pragma unroll
  for (int i = 0; i < 5; ++i)
#pragma unroll
    for (int j = 0; j < 6; ++j) {
      const int ua = lane + 64 * j;
      Dq[i][j] = (i < nr && ua < NU) ? Dg[(w + 8 * i) * KDIM + kA[j]] : 0.0f;
    }

  // ---- phase-2 D column (plus member) in registers
  float Dc[TT];
#pragma unroll
  for (int t = 0; t < TT; ++t) Dc[t] = act ? Dg[t * KDIM + kP] : 0.0f;

  // ---- c0 = Linv * (D^T x_col) via even/odd split; cm/cp thresholds
  float cmP, cpP, cmM, cpM;
  {
    float sE = 0.f, sO = 0.f;
#pragma unroll
    for (int t = 0; t < TT; ++t) {
      const float xv = X[t * PP + p];       // block-uniform: broadcast
      if (t & 1) sO = fmaf(Dc[t], xv, sO);
      else       sE = fmaf(Dc[t], xv, sE);
    }
    const float c0P = (sE + sO) * Linv, c0M = (sE - sO) * Linv;
    float wlP = lamL, wlM = lamL;
    if (!first) {
      const float nl = lamL * Lb[2];        // lam*Linv/||wr||
      wlP = nl / (fabsf(xprev[p * KPAD + kP]) + EPSW);
      wlM = nl / (fabsf(xprev[p * KPAD + ((u > 0) ? kM : kP)]) + EPSW);
    }
    cmP = c0P - wlP; cpP = c0P + wlP;
    cmM = c0M - wlM; cpM = c0M + wlM;
  }

  // ---- zero y in LDS (incl. pads: ZERO_SLOT must stay 0 forever)
  for (int i = tid; i < KPAD; i += BT) ylds[i] = 0.0f;

  float xP = 0.f, xM = 0.f, yP = 0.f, yM = 0.f;
  float tmom = 1.0f;

  __syncthreads();

  for (int it = 0; it < NITER; ++it) {
    // ===== phase 1: z = Linv * (D @ y), pole-paired; rows t = w + 8i =====
    float acc[5];
#pragma unroll
    for (int i = 0; i < 5; ++i) acc[i] = 0.f;
#pragma unroll
    for (int j = 0; j < 6; ++j) {
      const float yA = ylds[kA[j]];
      const float yB = ylds[kB[j]];
      const float op = fmaf(sgn, yB, yA);   // yA ± yB, parity wave-uniform
#pragma unroll
      for (int i = 0; i < 5; ++i) acc[i] = fmaf(Dq[i][j], op, acc[i]);
    }
#pragma unroll
    for (int i = 0; i < 5; ++i) {
      if (i < nr) {
        const float r = wave_sum63(acc[i]);
        if (lane == 63) zlds[w + 8 * i] = r * Linv;
      }
    }
    __syncthreads();

    // ===== phase 2: both rows of the pair via even/odd sums =====
    const float tn = 0.5f * (1.0f + sqrtf(1.0f + 4.0f * tmom * tmom));
    const float mu = (tmom - 1.0f) / tn;
    tmom = tn;

    if (act) {
      float sE = 0.f, sO = 0.f;
#pragma unroll
      for (int q = 0; q < 9; ++q) {
        const float4 z4 = *reinterpret_cast<const float4*>(&zlds[4 * q]);  // broadcast
        sE = fmaf(Dc[4*q+0], z4.x, sE);
        sO = fmaf(Dc[4*q+1], z4.y, sO);
        sE = fmaf(Dc[4*q+2], z4.z, sE);
        sO = fmaf(Dc[4*q+3], z4.w, sO);
      }
      const float sP = sE + sO, sM = sE - sO;
      float uu, xn;
      uu = yP - sP; xn = fmaxf(0.f, uu + cmP) + fminf(0.f, uu + cpP);
      yP = fmaf(mu, xn - xP, xn); xP = xn;
      uu = yM - sM; xn = fmaxf(0.f, uu + cmM) + fminf(0.f, uu + cpM);
      yM = fmaf(mu, xn - xM, xn); xM = xn;
      ylds[kP] = yP;
      ylds[kM] = yM;                        // u=0 dumps into DUMP_SLOT (never read)
    }
    __syncthreads();
  }

  // ---- emit x
  if (act) {
    if (last) {
      xout[kP * PP + p] = xP;
      if (u > 0) xout[kM * PP + p] = xM;
    } else {
      xout[p * KPAD + kP] = xP;             // transposed for next round's reads
      if (u > 0) xout[p * KPAD + kM] = xM;
    }
  }

  // ---- fused reweight-norm accumulation: sum of wr^2 over this column
  if (!last) {
    float s = 0.0f;
    if (act) {
      const float rP = 1.0f / (fabsf(xP) + EPSW);
      s = rP * rP;
      if (u > 0) { const float rM = 1.0f / (fabsf(xM) + EPSW); s += rM * rM; }
    }
    s = wave_sum63(s);
    if (lane == 63) zlds[w] = s;            // zlds free after the loop
    __syncthreads();
    if (tid == 0) {
      float tot = 0.f;
#pragma unroll
      for (int i = 0; i < 8; ++i) tot += zlds[i];
      atomicAdd(&Lb[3], tot);
    }
  }
}

// ---------------- finalize norm: Lb[2] = 1/||wr||, reset accumulator ----------------
__global__ void k_norm(float* __restrict__ Lb) {
  if (threadIdx.x == 0) {
    Lb[2] = 1.0f / sqrtf(Lb[3]);
    Lb[3] = 0.0f;
  }
}

// ---------------- host ----------------
extern "C" void kernel_launch(void* const* d_in, const int* in_sizes, int n_in,
                              void* d_out, int out_size, void* d_ws, size_t ws_size,
                              hipStream_t stream) {
  const float* x  = (const float*)d_in[0];
  const float* rr = (const float*)d_in[1];
  const float* th = (const float*)d_in[2];
  float* out = (float*)d_out;
  float* ws  = (float*)d_ws;

  size_t off = 0;
  auto alloc = [&](size_t n) {
    float* p = ws + off;
    off += (n + 63) & ~(size_t)63;
    return p;
  };
  float* D    = alloc((size_t)TT * KDIM);
  float* G    = alloc(TT * TT);
  float* Lb   = alloc(16);
  float* xa   = alloc((size_t)PP * KPAD);   // transposed intermediate x
  if (off * sizeof(float) > ws_size) return;

  k_build_dic<<<(TT * KDIM + 255) / 256, 256, 0, stream>>>(rr, th, D, out + (size_t)KDIM * PP);
  k_G<<<(TT * TT + 255) / 256, 256, 0, stream>>>(D, G);
  k_power<<<1, 64, 0, stream>>>(G, Lb);

  for (int r = 0; r < 3; ++r) {
    const int first = (r == 0), last = (r == 2);
    float* xo = last ? out : xa;
    k_round<<<PP, BT, 0, stream>>>(D, x, Lb, xa, xo, first, last);
    if (!last) k_norm<<<1, 64, 0, stream>>>(Lb);
  }
}

// Round 8
// 728.698 us; speedup vs baseline: 1.5894x; 1.1270x over previous
//
#include <hip/hip_runtime.h>
#include <math.h>

#define TT 36
#define NP 160
#define KDIM 641
#define PP 512
#define KPAD 704          // transposed-x row stride (pads unused)
#define NU 321            // pair-units: u=0 const col; 1..160 cos; 161..320 sin
#define YSLOTS 384        // float2 slots in ylds2 (covers ua up to 383 reads)
#define BT 512            // 8 waves
#define LAM 0.1f
#define EPSW 0.01f
#define NITER 200
#define NPOW 160

// ---------------- dictionary ----------------
__global__ void k_build_dic(const float* __restrict__ rr, const float* __restrict__ th,
                            float* __restrict__ D, float* __restrict__ outD) {
  int idx = blockIdx.x * blockDim.x + threadIdx.x;
  if (idx >= TT * KDIM) return;
  int t = idx / KDIM, k = idx % KDIM;
  float v;
  if (k == 0) {
    v = 1.0f;
  } else {
    int g = (k - 1) / NP;     // 0:p*cos 1:m*cos 2:p*sin 3:m*sin
    int p = (k - 1) % NP;
    float ft = (float)t;
    float pw = powf(rr[p], ft);
    if ((g == 1 || g == 3) && (t & 1)) pw = -pw;
    float ang = ft * th[p];
    v = pw * ((g < 2) ? cosf(ang) : sinf(ang));
  }
  D[idx] = v;
  outD[idx] = v;
}

// ---------------- G = D D^T (36x36) ----------------
__global__ void k_G(const float* __restrict__ D, float* __restrict__ G) {
  int idx = blockIdx.x * blockDim.x + threadIdx.x;
  if (idx >= TT * TT) return;
  int i = idx / TT, j = idx % TT;
  float s = 0.0f;
  for (int k = 0; k < KDIM; ++k) s = fmaf(D[i * KDIM + k], D[j * KDIM + k], s);
  G[idx] = s;
}

// ---------------- power iteration on 36x36 (one wave): L = ||DtD||_2; mu table ----------------
__global__ void k_power(const float* __restrict__ G, float* __restrict__ Lb,
                        float* __restrict__ mug) {
  int lane = threadIdx.x;   // blockDim = 64
  float g[TT];
#pragma unroll
  for (int j = 0; j < TT; ++j) g[j] = (lane < TT) ? G[lane * TT + j] : 0.0f;
  float v = (lane < TT) ? 1.0f : 0.0f;
  for (int it = 0; it < NPOW; ++it) {
    float u = 0.0f;
#pragma unroll
    for (int j = 0; j < TT; ++j) u = fmaf(g[j], __shfl(v, j, 64), u);
    float s = u * u;
#pragma unroll
    for (int o = 32; o >= 1; o >>= 1) s += __shfl_xor(s, o, 64);
    v = u * rsqrtf(s);
  }
  float u = 0.0f;
#pragma unroll
  for (int j = 0; j < TT; ++j) u = fmaf(g[j], __shfl(v, j, 64), u);
  float num = v * u, den = v * v;
#pragma unroll
  for (int o = 32; o >= 1; o >>= 1) {
    num += __shfl_xor(num, o, 64);
    den += __shfl_xor(den, o, 64);
  }
  if (lane == 0) {
    float L = num / den;   // Rayleigh quotient = lambda_max
    Lb[0] = L;
    Lb[1] = 1.0f / L;
    Lb[3] = 0.0f;          // reset norm accumulator (graph-replay safe)
    // FISTA momentum schedule
    float t = 1.0f;
    for (int i = 0; i < NITER; ++i) {
      float tn = 0.5f * (1.0f + sqrtf(1.0f + 4.0f * t * t));
      mug[i] = (t - 1.0f) / tn;
      t = tn;
    }
  }
}

// ---- DPP wave-64 sum; total valid in lane 63 ----
template <int C>
__device__ __forceinline__ float dppadd(float v) {
  int t = __builtin_amdgcn_update_dpp(0, __float_as_int(v), C, 0xf, 0xf, true);
  return v + __int_as_float(t);
}
__device__ __forceinline__ float wave_sum63(float v) {
  v = dppadd<0xB1>(v);    // quad_perm [1,0,3,2]
  v = dppadd<0x4E>(v);    // quad_perm [2,3,0,1]
  v = dppadd<0x141>(v);   // row_half_mirror
  v = dppadd<0x140>(v);   // row_mirror
  v = dppadd<0x142>(v);   // row_bcast15
  v = dppadd<0x143>(v);   // row_bcast31
  return v;
}

// plus-group column index of pair-unit u (u < NU)
__device__ __forceinline__ int colmap(int u) {
  return (u == 0) ? 0 : ((u < 161) ? u : u + 160);
}

// ---------------- persistent per-round FISTA: one column per block, 8 waves ----------------
__global__ __attribute__((amdgpu_flat_work_group_size(BT, BT), amdgpu_waves_per_eu(4, 4)))
void k_round(
    const float* __restrict__ Dg, const float* __restrict__ X,
    float* __restrict__ Lb, const float* __restrict__ mug,
    const float* __restrict__ xprev, float* __restrict__ xout,
    int first, int last) {
  __shared__ __align__(16) float2 ylds2[YSLOTS];   // slot u = (yP_u, yM_u)
  __shared__ __align__(16) float zlds[40];
  __shared__ float muLDS[NITER];

  const int tid  = threadIdx.x;
  const int lane = tid & 63;
  const int w    = tid >> 6;          // wave 0..7
  const int nr   = (w < 4) ? 5 : 4;   // rows owned: t = w + 8i, i < nr
  const float sgn = (w & 1) ? -1.0f : 1.0f;   // row parity uniform per wave
  const int p    = blockIdx.x;        // column

  const float Linv = Lb[1];
  const float lamL = LAM * Linv;

  // ---- phase-2 pair-unit: one per thread (tid < NU)
  const int u = tid;
  const bool act = (u < NU);
  const int kP = colmap(act ? u : 0);
  const int kM = (u == 0 || !act) ? 0 : kP + 160;   // minus-group row (guarded by u>0)

  // ---- phase-1 Dq: rows t = w+8i, plus-column of unit ua = lane + 64j
  float Dq[5][6];
#pragma unroll
  for (int i = 0; i < 5; ++i)
#pragma unroll
    for (int j = 0; j < 6; ++j) {
      const int ua = lane + 64 * j;
      Dq[i][j] = (i < nr && ua < NU) ? Dg[(w + 8 * i) * KDIM + colmap(ua)] : 0.0f;
    }
#pragma unroll
  for (int i = 0; i < 5; ++i)
#pragma unroll
    for (int j = 0; j < 6; ++j)
      asm volatile("v_mov_b32 %0, %0" : "+v"(Dq[i][j]));   // pin: no remat/reload

  // ---- phase-2 D column (plus member) in registers, pinned
  float Dc[TT];
#pragma unroll
  for (int t = 0; t < TT; ++t) Dc[t] = act ? Dg[t * KDIM + kP] : 0.0f;
#pragma unroll
  for (int t = 0; t < TT; ++t)
    asm volatile("v_mov_b32 %0, %0" : "+v"(Dc[t]));        // pin: no remat/reload

  // ---- c0 = Linv * (D^T x_col) via even/odd split; cm/cp thresholds
  float cmP, cpP, cmM, cpM;
  {
    float sE = 0.f, sO = 0.f;
#pragma unroll
    for (int t = 0; t < TT; ++t) {
      const float xv = X[t * PP + p];       // block-uniform: broadcast
      if (t & 1) sO = fmaf(Dc[t], xv, sO);
      else       sE = fmaf(Dc[t], xv, sE);
    }
    const float c0P = (sE + sO) * Linv, c0M = (sE - sO) * Linv;
    float wlP = lamL, wlM = lamL;
    if (!first) {
      const float nl = lamL * Lb[2];        // lam*Linv/||wr||
      wlP = nl / (fabsf(xprev[p * KPAD + kP]) + EPSW);
      wlM = nl / (fabsf(xprev[p * KPAD + ((u > 0) ? kM : kP)]) + EPSW);
    }
    cmP = c0P - wlP; cpP = c0P + wlP;
    cmM = c0M - wlM; cpM = c0M + wlM;
  }

  // ---- stage mu table; zero y pairs (incl. pad slots, read by inactive lanes)
  if (tid < NITER) muLDS[tid] = mug[tid];
  if (tid < YSLOTS) ylds2[tid] = make_float2(0.f, 0.f);

  float xP = 0.f, xM = 0.f, yP = 0.f, yM = 0.f;

  __syncthreads();

  for (int it = 0; it < NITER; ++it) {
    // ===== phase 1: z = Linv * (D @ y), pole-paired; rows t = w + 8i =====
    float acc[5];
#pragma unroll
    for (int i = 0; i < 5; ++i) acc[i] = 0.f;
#pragma unroll
    for (int j = 0; j < 6; ++j) {
      const float2 yv = ylds2[lane + 64 * j];   // ds_read_b64: base + imm offset
      const float op = fmaf(sgn, yv.y, yv.x);   // yP ± yM, parity wave-uniform
#pragma unroll
      for (int i = 0; i < 5; ++i) acc[i] = fmaf(Dq[i][j], op, acc[i]);
    }
#pragma unroll
    for (int i = 0; i < 5; ++i) {
      if (i < nr) {
        const float r = wave_sum63(acc[i]);
        if (lane == 63) zlds[w + 8 * i] = r * Linv;
      }
    }
    __syncthreads();

    // ===== phase 2: both rows of the pair via even/odd sums =====
    const float mu = muLDS[it];
    if (act) {
      float sE = 0.f, sO = 0.f;
#pragma unroll
      for (int q = 0; q < 9; ++q) {
        const float4 z4 = *reinterpret_cast<const float4*>(&zlds[4 * q]);  // broadcast
        sE = fmaf(Dc[4*q+0], z4.x, sE);
        sO = fmaf(Dc[4*q+1], z4.y, sO);
        sE = fmaf(Dc[4*q+2], z4.z, sE);
        sO = fmaf(Dc[4*q+3], z4.w, sO);
      }
      const float sP = sE + sO, sM = sE - sO;
      float uu, xn;
      uu = yP - sP; xn = fmaxf(0.f, uu + cmP) + fminf(0.f, uu + cpP);
      yP = fmaf(mu, xn - xP, xn); xP = xn;
      uu = yM - sM; xn = fmaxf(0.f, uu + cmM) + fminf(0.f, uu + cpM);
      yM = fmaf(mu, xn - xM, xn); xM = xn;
      const float yMs = (u == 0) ? 0.0f : yM;   // unit 0 has no minus-row
      ylds2[u] = make_float2(yP, yMs);          // ds_write_b64
    }
    __syncthreads();
  }

  // ---- emit x
  if (act) {
    if (last) {
      xout[kP * PP + p] = xP;
      if (u > 0) xout[kM * PP + p] = xM;
    } else {
      xout[p * KPAD + kP] = xP;             // transposed for next round's reads
      if (u > 0) xout[p * KPAD + kM] = xM;
    }
  }

  // ---- fused reweight-norm accumulation: sum of wr^2 over this column
  if (!last) {
    float s = 0.0f;
    if (act) {
      const float rP = 1.0f / (fabsf(xP) + EPSW);
      s = rP * rP;
      if (u > 0) { const float rM = 1.0f / (fabsf(xM) + EPSW); s += rM * rM; }
    }
    s = wave_sum63(s);
    if (lane == 63) zlds[w] = s;            // zlds free after the loop
    __syncthreads();
    if (tid == 0) {
      float tot = 0.f;
#pragma unroll
      for (int i = 0; i < 8; ++i) tot += zlds[i];
      atomicAdd(&Lb[3], tot);
    }
  }
}

// ---------------- finalize norm: Lb[2] = 1/||wr||, reset accumulator ----------------
__global__ void k_norm(float* __restrict__ Lb) {
  if (threadIdx.x == 0) {
    Lb[2] = 1.0f / sqrtf(Lb[3]);
    Lb[3] = 0.0f;
  }
}

// ---------------- host ----------------
extern "C" void kernel_launch(void* const* d_in, const int* in_sizes, int n_in,
                              void* d_out, int out_size, void* d_ws, size_t ws_size,
                              hipStream_t stream) {
  const float* x  = (const float*)d_in[0];
  const float* rr = (const float*)d_in[1];
  const float* th = (const float*)d_in[2];
  float* out = (float*)d_out;
  float* ws  = (float*)d_ws;

  size_t off = 0;
  auto alloc = [&](size_t n) {
    float* p = ws + off;
    off += (n + 63) & ~(size_t)63;
    return p;
  };
  float* D    = alloc((size_t)TT * KDIM);
  float* G    = alloc(TT * TT);
  float* Lb   = alloc(16);
  float* mug  = alloc(NITER);
  float* xa   = alloc((size_t)PP * KPAD);   // transposed intermediate x
  if (off * sizeof(float) > ws_size) return;

  k_build_dic<<<(TT * KDIM + 255) / 256, 256, 0, stream>>>(rr, th, D, out + (size_t)KDIM * PP);
  k_G<<<(TT * TT + 255) / 256, 256, 0, stream>>>(D, G);
  k_power<<<1, 64, 0, stream>>>(G, Lb, mug);

  for (int r = 0; r < 3; ++r) {
    const int first = (r == 0), last = (r == 2);
    float* xo = last ? out : xa;
    k_round<<<PP, BT, 0, stream>>>(D, x, Lb, mug, xa, xo, first, last);
    if (!last) k_norm<<<1, 64, 0, stream>>>(Lb);
  }
}